// Round 3
// baseline (1030.501 us; speedup 1.0000x reference)
//
#include <hip/hip_runtime.h>
#include <stdint.h>
#include <stddef.h>

// GraphConvolution: out = relu(S @ S @ S @ ((x .* mask / 0.9) @ W))
//   x: [16384,512] f32, S: [16384,16384] f32, W: [512,128] f32, mask: [16384,512] f32
// bf16 MFMA (16x16x32); S converted fp32->bf16 in registers (3 streaming passes of
// 1.07 GB => ~515us HBM floor). Feat kept transposed bf16 FT[128][16384].
// No K-split: BM=32, grid 512 (2 blocks/CU), full-K fp32 accumulation per block,
// direct FT/out write in epilogue. 5 dispatches, no partial buffers.
// Sync schedule: DMA issued after barrier t, drained by an EXPLICIT
// s_waitcnt vmcnt(0) just before barrier t+1 (no reliance on fence lowering).

#define NROWS 16384
#define KDIN  512
#define NDOUT 128

typedef __attribute__((ext_vector_type(8))) short bf16x8;
typedef __attribute__((ext_vector_type(4))) float f32x4;
typedef __attribute__((ext_vector_type(4))) unsigned short u16x4;

__device__ __forceinline__ unsigned short f2bf(float f) {
  union { float f; unsigned u; } v; v.f = f;
  unsigned r = v.u + 0x7FFFu + ((v.u >> 16) & 1u);   // RNE
  return (unsigned short)(r >> 16);
}

__device__ __forceinline__ void gld_lds16(const void* g, void* l) {
  __builtin_amdgcn_global_load_lds(
      (const __attribute__((address_space(1))) void*)g,
      (__attribute__((address_space(3))) void*)l, 16, 0, 0);
}

__device__ __forceinline__ float4 dmul(float4 a, float4 m) {
  const float s = (float)(1.0 / 0.9);
  float4 r; r.x = a.x*m.x*s; r.y = a.y*m.y*s; r.z = a.z*m.z*s; r.w = a.w*m.w*s;
  return r;
}

// C[32 x 128] = A-rows (f32, optionally .*mask/0.9) @ B, B given transposed bf16
// BT[128][ldb]. 256 threads = 4 waves: wave w -> row-group (w&1)*16, n-half (w>>1)*64.
// OUT=0: write bf16 FT[128][16384] (transposed). OUT=1: write relu fp32 out[16384][128].
template<int DROP, int OUT>
__global__ __launch_bounds__(256, 2)
void gemm32(const float* __restrict__ A, const float* __restrict__ Am,
            const unsigned short* __restrict__ BT,
            int lda, int ldb, int K,
            unsigned short* __restrict__ FT, float* __restrict__ out)
{
  __shared__ unsigned short ldsB[2 * 8192];   // 2 x [128 n][64 k] bf16 = 32 KiB
  const int tid = threadIdx.x;
  const int w = tid >> 6, l = tid & 63;
  const int g = l >> 4, lm = l & 15;
  const int rg = w & 1, nh = w >> 1;
  const int mtile = blockIdx.x;
  const int nst = K >> 6;

  // A: lane owns row (mtile*32 + rg*16 + lm), k-offset g*8 within each 32-k chunk
  const int arow = mtile * 32 + rg * 16 + lm;
  const float* ap = A + (size_t)arow * lda + g * 8;
  const float* mp = DROP ? (Am + (size_t)arow * lda + g * 8) : (const float*)0;

  // B staging: 4 x 16B per thread per stage; source pre-swizzled (chunk c XOR n&7)
  // so LDS stays linear for global_load_lds; read side applies the same XOR.
  const unsigned short* bs[4];
  #pragma unroll
  for (int j = 0; j < 4; ++j) {
    const int n = (tid >> 3) + j * 32, c = tid & 7;
    bs[j] = BT + (size_t)n * ldb + ((c ^ (n & 7)) << 3);
  }

  f32x4 acc[4];
  #pragma unroll
  for (int i = 0; i < 4; ++i) acc[i] = (f32x4){0.f, 0.f, 0.f, 0.f};

  float4 cur0, cur1, cur2, cur3;
  float4 nxt0 = {0,0,0,0}, nxt1 = {0,0,0,0}, nxt2 = {0,0,0,0}, nxt3 = {0,0,0,0};

  // prologue: stage 0 -> buf0 + A regs
  {
    unsigned short* d = ldsB + tid * 8;
    #pragma unroll
    for (int j = 0; j < 4; ++j) gld_lds16(bs[j], d + j * 2048);
    cur0 = *(const float4*)(ap);
    cur1 = *(const float4*)(ap + 4);
    cur2 = *(const float4*)(ap + 32);
    cur3 = *(const float4*)(ap + 36);
    if (DROP) {
      cur0 = dmul(cur0, *(const float4*)(mp));
      cur1 = dmul(cur1, *(const float4*)(mp + 4));
      cur2 = dmul(cur2, *(const float4*)(mp + 32));
      cur3 = dmul(cur3, *(const float4*)(mp + 36));
    }
  }

  for (int t = 0; t < nst; ++t) {
    // Explicit drain: all DMA (B stage t) + A prefetch (stage t) issued last
    // iteration have landed. Then barrier. Provably safe independent of how
    // __syncthreads lowers its fence.
    asm volatile("s_waitcnt vmcnt(0)" ::: "memory");
    __syncthreads();
    if (t + 1 < nst) {
      unsigned short* d = ldsB + ((t + 1) & 1) * 8192 + tid * 8;
      #pragma unroll
      for (int j = 0; j < 4; ++j) gld_lds16(bs[j] + (size_t)(t + 1) * 64, d + j * 2048);
      const float* p = ap + (size_t)(t + 1) * 64;
      nxt0 = *(const float4*)(p);
      nxt1 = *(const float4*)(p + 4);
      nxt2 = *(const float4*)(p + 32);
      nxt3 = *(const float4*)(p + 36);
      if (DROP) {
        const float* q = mp + (size_t)(t + 1) * 64;
        nxt0 = dmul(nxt0, *(const float4*)(q));
        nxt1 = dmul(nxt1, *(const float4*)(q + 4));
        nxt2 = dmul(nxt2, *(const float4*)(q + 32));
        nxt3 = dmul(nxt3, *(const float4*)(q + 36));
      }
    }
    const char* lb = (const char*)ldsB + (t & 1) * 16384;
    #pragma unroll
    for (int kk = 0; kk < 2; ++kk) {
      const float4 u = kk ? cur2 : cur0;
      const float4 v = kk ? cur3 : cur1;
      bf16x8 af;
      af[0] = (short)f2bf(u.x); af[1] = (short)f2bf(u.y);
      af[2] = (short)f2bf(u.z); af[3] = (short)f2bf(u.w);
      af[4] = (short)f2bf(v.x); af[5] = (short)f2bf(v.y);
      af[6] = (short)f2bf(v.z); af[7] = (short)f2bf(v.w);
      #pragma unroll
      for (int nt = 0; nt < 4; ++nt) {
        const int n = nh * 64 + nt * 16 + lm;
        const int off = n * 128 + (((kk << 6) + (g << 4)) ^ ((n & 7) << 4));
        bf16x8 bf = *(const bf16x8*)(lb + off);
        acc[nt] = __builtin_amdgcn_mfma_f32_16x16x32_bf16(af, bf, acc[nt], 0, 0, 0);
      }
    }
    if (t + 1 < nst) { cur0 = nxt0; cur1 = nxt1; cur2 = nxt2; cur3 = nxt3; }
  }

  // C frag layout: col = lane&15 (= lm), row = (lane>>4)*4 + r (= g*4+r)
  if (OUT == 0) {
    const int m0 = mtile * 32 + rg * 16 + g * 4;
    #pragma unroll
    for (int nt = 0; nt < 4; ++nt) {
      const int n = nh * 64 + nt * 16 + lm;
      u16x4 vv;
      vv[0] = f2bf(acc[nt][0]); vv[1] = f2bf(acc[nt][1]);
      vv[2] = f2bf(acc[nt][2]); vv[3] = f2bf(acc[nt][3]);
      *(u16x4*)(FT + (size_t)n * NROWS + m0) = vv;
    }
  } else {
    float* po = out + ((size_t)mtile * 32 + rg * 16) * NDOUT;
    #pragma unroll
    for (int nt = 0; nt < 4; ++nt) {
      #pragma unroll
      for (int r = 0; r < 4; ++r) {
        po[(g * 4 + r) * NDOUT + nh * 64 + nt * 16 + lm] = fmaxf(acc[nt][r], 0.f);
      }
    }
  }
}

// W [512][128] f32 -> WT [128][512] bf16
__global__ void wconv(const float* __restrict__ W, unsigned short* __restrict__ WT)
{
  const int t = blockIdx.x * 256 + threadIdx.x;   // 65536
  const int n = t & 127, k = t >> 7;
  WT[(size_t)n * KDIN + k] = f2bf(W[(size_t)k * NDOUT + n]);
}

extern "C" void kernel_launch(void* const* d_in, const int* in_sizes, int n_in,
                              void* d_out, int out_size, void* d_ws, size_t ws_size,
                              hipStream_t stream)
{
  const float* x       = (const float*)d_in[0];
  const float* support = (const float*)d_in[1];
  const float* weight  = (const float*)d_in[2];
  const float* dmask   = (const float*)d_in[3];
  float* out = (float*)d_out;
  char* ws = (char*)d_ws;

  // ws layout: FTa 4MiB | FTb 4MiB | WT 128KiB  (= 8.125 MiB used)
  unsigned short* FTa = (unsigned short*)(ws);
  unsigned short* FTb = (unsigned short*)(ws + (size_t)(4 << 20));
  unsigned short* WT  = (unsigned short*)(ws + (size_t)(8 << 20));

  // 1. W -> WT (transposed bf16)
  wconv<<<256, 256, 0, stream>>>(weight, WT);
  // 2. pre_sup = (x .* mask / 0.9) @ W  -> FTa (bf16, transposed)
  gemm32<1, 0><<<512, 256, 0, stream>>>(x, dmask, WT, KDIN, KDIN, KDIN, FTa, (float*)0);
  // 3. three diffusion steps: feat <- S @ feat (full-K, no split)
  gemm32<0, 0><<<512, 256, 0, stream>>>(support, (const float*)0, FTa, NROWS, NROWS, NROWS, FTb, (float*)0);
  gemm32<0, 0><<<512, 256, 0, stream>>>(support, (const float*)0, FTb, NROWS, NROWS, NROWS, FTa, (float*)0);
  // 4. last step fused with relu -> d_out fp32
  gemm32<0, 1><<<512, 256, 0, stream>>>(support, (const float*)0, FTa, NROWS, NROWS, NROWS, (unsigned short*)0, out);
  (void)in_sizes; (void)n_in; (void)out_size; (void)ws_size;
}